// Round 7
// baseline (27.226 us; speedup 1.0000x reference)
//
#include <hip/hip_runtime.h>

#define NB 64
#define NT 512
#define HIDDEN 512
#define TF 861            // 22050*10/256
#define CHUNKS 32
#define FPC 27            // frames per chunk (last chunk: 24 real)
#define GRID (NB * CHUNKS)   // 2048, divisible by 8, = 8 blocks/CU

typedef float v4f __attribute__((ext_vector_type(4)));   // native vector: ok for nontemporal builtins

// Fully fused. Per block: shuffle-scan 512 durations (2/thread), scatter
// frame->idx from registers, then each WAVE copies a CONTIGUOUS run of 7
// frames, register-caching the current row (rows repeat ~5 consecutive
// frames) and using nontemporal stores (output is write-once).
__global__ __launch_bounds__(256) void lr_fused(const float* __restrict__ pred,
                                                const v4f* __restrict__ batch4,
                                                v4f* __restrict__ out4) {
    __shared__ int wsum[4];
    __shared__ int sidx[28];

    // XCD-chunked swizzle: each XCD owns a contiguous (b,chunk) range
    const int bid = blockIdx.x;
    const int sid = (bid & 7) * (GRID >> 3) + (bid >> 3);
    const int b = sid >> 5;           // CHUNKS == 32
    const int chunk = sid & 31;
    const int base = chunk * FPC;

    const int t = threadIdx.x;
    const int lane = t & 63;
    const int wid = t >> 6;

    // ---- duration scan: 512 entries, 2 per thread, shuffle-based ----
    float2 p2 = ((const float2*)(pred + b * NT))[t];
    int d0 = (int)rintf(fminf(fmaxf(p2.x, 1.f), 10.f));   // round-half-even
    int d1 = (int)rintf(fminf(fmaxf(p2.y, 1.f), 10.f));
    int x = d0 + d1;
    #pragma unroll
    for (int off = 1; off < 64; off <<= 1) {
        int y = __shfl_up(x, off, 64);
        if (lane >= off) x += y;
    }
    if (lane == 63) wsum[wid] = x;
    if (t < 28) sidx[t] = -1;
    __syncthreads();
    int prefix = 0;
    #pragma unroll
    for (int w = 0; w < 3; ++w)
        if (w < wid) prefix += wsum[w];
    x += prefix;

    // ---- scatter: element e covers frames [ends[e-1], ends[e]) ----
    const int end1   = x;             // ends[2t+1]
    const int start1 = x - d1;        // ends[2t]
    const int start0 = start1 - d0;   // ends[2t-1]
    const int wend = min(base + FPC, TF);
    {
        int lo = max(start0, base), hi = min(start1, wend);
        for (int f = lo; f < hi; ++f) sidx[f - base] = 2 * t;
        lo = max(start1, base); hi = min(end1, wend);
        for (int f = lo; f < hi; ++f) sidx[f - base] = 2 * t + 1;
    }
    __syncthreads();

    // ---- copy: wave owns contiguous run of 7 frames; register row-cache ----
    const int nv = wend - base;            // valid frame count this chunk
    const int run0 = wid * 7;
    const v4f* srcb = batch4 + ((size_t)b << 16);          // b*512*128
    v4f* dstb = out4 + (((size_t)b * TF + base) << 7);

    // preload run's indices into named registers (no runtime indexing)
    const int i0 = sidx[run0 + 0], i1 = sidx[run0 + 1], i2 = sidx[run0 + 2],
              i3 = sidx[run0 + 3], i4 = sidx[run0 + 4], i5 = sidx[run0 + 5],
              i6 = sidx[run0 + 6];

    int curidx = -2;
    v4f v0 = (v4f)(0.f), v1 = (v4f)(0.f);

#define STEP(K, IK)                                                     \
    if (run0 + (K) < nv) {                                              \
        if ((IK) != curidx) {                                           \
            curidx = (IK);                                              \
            if ((IK) >= 0) {                                            \
                const v4f* src = srcb + ((size_t)(IK) << 7);            \
                v0 = src[lane];                                         \
                v1 = src[lane + 64];                                    \
            } else {                                                    \
                v0 = (v4f)(0.f); v1 = (v4f)(0.f);                       \
            }                                                           \
        }                                                               \
        v4f* dst = dstb + ((size_t)(run0 + (K)) << 7);                  \
        __builtin_nontemporal_store(v0, dst + lane);                    \
        __builtin_nontemporal_store(v1, dst + lane + 64);               \
    }

    STEP(0, i0) STEP(1, i1) STEP(2, i2) STEP(3, i3)
    STEP(4, i4) STEP(5, i5) STEP(6, i6)
#undef STEP
}

extern "C" void kernel_launch(void* const* d_in, const int* in_sizes, int n_in,
                              void* d_out, int out_size, void* d_ws, size_t ws_size,
                              hipStream_t stream) {
    const float* batch = (const float*)d_in[0];
    const float* pred  = (const float*)d_in[1];
    float* out = (float*)d_out;

    lr_fused<<<GRID, 256, 0, stream>>>(pred, (const v4f*)batch, (v4f*)out);
}